// Round 1
// baseline (911.314 us; speedup 1.0000x reference)
//
#include <hip/hip_runtime.h>
#include <hip/hip_bf16.h>
#include <hip/hip_fp16.h>

// Decoder_22273700397282 on MI355X (gfx950)
// out[b,f] = trigger_a[b,f] * sum_t softmax_f(tanh(a@Wa + ba + s@Ws + bs))[t,f]
// with mask==0 rows -> uniform 1/3072 (all-(-1e9) row).
//
// Pipeline:
//  k_sum_h   : s[b,k]   = sum_t h_state[b,t,k]                (fp32)
//  k_base    : base[b,f]= s@Ws + ba + bs                      (fp32, exact-ish)
//  k_cvt_a   : Abf[r,k] = bf16(concat(h_state,x)[r,k])        (r = b*512+t)
//  k_wat     : WaT[f,k] = bf16(Wa[k,f])                       (transpose for k-contig frags)
//  k_gemm    : P[r,f] = mask? exp(tanh(Abf@Wa + base)) : 1    (fp16), Dpart[r, f/64] rowsums
//  k_invd    : invD[r] = 1/sum_nb Dpart[r,nb]
//  k_final   : out[b,f] = trig_a[b,f] * sum_t P[r,f]*invD[r]

namespace {
constexpr int SIN  = 1024;            // IN_SIZE
constexpr int KH   = 2048;            // 2*IN (h_state feature dim)
constexpr int NF   = 3072;            // 3*IN = OUT_SIZE = GEMM K and N
constexpr int NBAT = 32;              // B
constexpr int NS   = 512;             // S
constexpr int NM   = NBAT * NS;       // 16384 GEMM rows
constexpr int NDB  = NF / 64;         // 48 Dpart column blocks
}

typedef unsigned short u16;
typedef __bf16 bf16x8 __attribute__((ext_vector_type(8)));
typedef float  f32x4  __attribute__((ext_vector_type(4)));

#define ASYNC_CP16(gptr, lptr)                                                              \
  __builtin_amdgcn_global_load_lds((__attribute__((address_space(1))) void*)(gptr),         \
                                   (__attribute__((address_space(3))) void*)(lptr), 16, 0, 0)

__device__ __forceinline__ u16 f2b(float f) {
  union { float f; unsigned u; } v; v.f = f;
  unsigned u = v.u;
  u += 0x7FFFu + ((u >> 16) & 1u);     // round-to-nearest-even
  return (u16)(u >> 16);
}

// ---------------- s[b,k] = sum_t h[b,t,k] ----------------
__global__ __launch_bounds__(256) void k_sum_h(const float* __restrict__ h,
                                               float* __restrict__ s) {
  int b = blockIdx.x;
  int d = blockIdx.y * 256 + threadIdx.x;          // d < 2048
  const float* p = h + (size_t)b * NS * KH + d;
  float acc = 0.f;
#pragma unroll 8
  for (int t = 0; t < NS; ++t) acc += p[(size_t)t * KH];
  s[b * KH + d] = acc;
}

// ---------------- base[b,f] = s@Ws + ba + bs ----------------
__global__ __launch_bounds__(256) void k_base(const float* __restrict__ s,
                                              const float* __restrict__ Ws,
                                              const float* __restrict__ ba,
                                              const float* __restrict__ bs,
                                              float* __restrict__ base) {
  int b = blockIdx.x;
  int f = blockIdx.y * 256 + threadIdx.x;          // f < 3072
  const float* sb = s + b * KH;
  float acc = 0.f;
#pragma unroll 4
  for (int k = 0; k < KH; ++k) acc += sb[k] * Ws[(size_t)k * NF + f];
  base[b * NF + f] = acc + ba[f] + bs[f];
}

// ---------------- Abf[r,k] = bf16(concat(h,x)) ----------------
__global__ __launch_bounds__(256) void k_cvt_a(const float* __restrict__ h,
                                               const float* __restrict__ x,
                                               u16* __restrict__ A) {
  int tid = blockIdx.x * 256 + threadIdx.x;        // over NM * (NF/4)
  int r = tid / (NF / 4);
  int k = (tid - r * (NF / 4)) * 4;
  int b = r >> 9, t = r & 511;
  const float* src = (k < KH) ? h + ((size_t)b * NS + t) * KH + k
                              : x + ((size_t)b * NS + t) * SIN + (k - KH);
  float4 v = *(const float4*)src;
  ushort4 o;
  o.x = f2b(v.x); o.y = f2b(v.y); o.z = f2b(v.z); o.w = f2b(v.w);
  *(ushort4*)(A + (size_t)r * NF + k) = o;
}

// ---------------- WaT[f,k] = bf16(Wa[k,f]) ----------------
__global__ __launch_bounds__(256) void k_wat(const float* __restrict__ Wa,
                                             u16* __restrict__ WaT) {
  __shared__ float tile[64][65];
  int k0 = blockIdx.x * 64, f0 = blockIdx.y * 64;
  int tid = threadIdx.x;
  int col4 = (tid & 15) * 4, row = tid >> 4;       // 16 rows per pass
#pragma unroll
  for (int rr = 0; rr < 64; rr += 16) {
    float4 v = *(const float4*)(Wa + (size_t)(k0 + row + rr) * NF + f0 + col4);
    tile[row + rr][col4 + 0] = v.x; tile[row + rr][col4 + 1] = v.y;
    tile[row + rr][col4 + 2] = v.z; tile[row + rr][col4 + 3] = v.w;
  }
  __syncthreads();
#pragma unroll
  for (int rr = 0; rr < 64; rr += 16) {
    int f = f0 + row + rr;
    ushort4 o;
    o.x = f2b(tile[col4 + 0][row + rr]); o.y = f2b(tile[col4 + 1][row + rr]);
    o.z = f2b(tile[col4 + 2][row + rr]); o.w = f2b(tile[col4 + 3][row + rr]);
    *(ushort4*)(WaT + (size_t)f * NF + k0 + col4) = o;
  }
}

// ---------------- main GEMM + tanh/exp epilogue ----------------
// C[r,c] = Abf[r,:] @ WaT[c,:]^T ; 128x128 tile, BK=64, 4 waves (2x2), m97 structure.
__global__ __launch_bounds__(256) void k_gemm(const u16* __restrict__ A,
                                              const u16* __restrict__ Wt,
                                              const float* __restrict__ base,
                                              const int* __restrict__ mask,
                                              __half* __restrict__ P,
                                              float* __restrict__ Dpart) {
  __shared__ __align__(16) u16 Asm[128 * 64];
  __shared__ __align__(16) u16 Bsm[128 * 64];
  const int tid  = threadIdx.x;
  const int wid  = tid >> 6, lane = tid & 63;
  const int wr   = wid >> 1, wc = wid & 1;         // 2x2 wave grid, each 64x64
  const int g    = lane >> 4, lr = lane & 15;
  const int r0   = blockIdx.y * 128;               // M tile (16384/128 = 128)
  const int c0   = blockIdx.x * 128;               // N tile (3072/128 = 24)

  f32x4 acc[4][4] = {};

  for (int kt = 0; kt < NF; kt += 64) {
#pragma unroll
    for (int q = 0; q < 4; ++q) {
      int cidx = q * 256 + tid;                    // 16B chunk id, 0..1023
      int arow = cidx >> 3;                        // 0..127
      int akb  = (cidx & 7) * 8;                   // u16 offset in row, 0..56
      const u16* ga = A  + (size_t)(r0 + arow) * NF + kt + akb;
      const u16* gb = Wt + (size_t)(c0 + arow) * NF + kt + akb;
      // wave-uniform LDS base; HW adds lane*16B
      ASYNC_CP16(ga, Asm + q * 2048 + wid * 512);
      ASYNC_CP16(gb, Bsm + q * 2048 + wid * 512);
    }
    __syncthreads();                               // compiler emits vmcnt(0) drain
#pragma unroll
    for (int kk = 0; kk < 64; kk += 32) {
      bf16x8 af[4], bf[4];
#pragma unroll
      for (int m = 0; m < 4; ++m)
        af[m] = *(const bf16x8*)&Asm[(wr * 64 + m * 16 + lr) * 64 + kk + g * 8];
#pragma unroll
      for (int n = 0; n < 4; ++n)
        bf[n] = *(const bf16x8*)&Bsm[(wc * 64 + n * 16 + lr) * 64 + kk + g * 8];
#pragma unroll
      for (int m = 0; m < 4; ++m)
#pragma unroll
        for (int n = 0; n < 4; ++n)
          acc[m][n] = __builtin_amdgcn_mfma_f32_16x16x32_bf16(af[m], bf[n], acc[m][n], 0, 0, 0);
    }
    __syncthreads();
  }

  // epilogue: z = acc + base[b,c]; P = mask ? exp(tanh(z)) : 1; Dpart rowsums
  const int b = r0 >> 9;                           // 512 % 128 == 0 -> uniform per block
  const int cbase = c0 + wc * 64;
  int   cc[4];
  float bse[4];
#pragma unroll
  for (int n = 0; n < 4; ++n) {
    cc[n]  = cbase + n * 16 + lr;
    bse[n] = base[b * NF + cc[n]];
  }
#pragma unroll
  for (int m = 0; m < 4; ++m) {
#pragma unroll
    for (int j = 0; j < 4; ++j) {
      int r  = r0 + wr * 64 + m * 16 + g * 4 + j;
      int t  = r & 511;
      int mk = mask[b * NS + t];
      float rs = 0.f;
#pragma unroll
      for (int n = 0; n < 4; ++n) {
        float p;
        if (mk) {
          float z  = acc[m][n][j] + bse[n];
          z        = fminf(fmaxf(z, -15.f), 15.f);
          float e2 = __expf(2.f * z);
          float th = (e2 - 1.f) / (e2 + 1.f);      // tanh(z)
          p        = __expf(th);
        } else {
          p = 1.0f;
        }
        P[(size_t)r * NF + cc[n]] = __float2half(p);
        rs += p;
      }
      // reduce rs across the 16 lanes sharing this row (lr dimension)
#pragma unroll
      for (int off = 1; off < 16; off <<= 1) rs += __shfl_xor(rs, off, 64);
      if (lr == 0) Dpart[(size_t)r * NDB + (cbase >> 6)] = rs;
    }
  }
}

// ---------------- invD[r] = 1 / sum_nb Dpart[r,nb] ----------------
__global__ __launch_bounds__(256) void k_invd(const float* __restrict__ Dpart,
                                              float* __restrict__ invD) {
  int r = blockIdx.x * 256 + threadIdx.x;
  float d = 0.f;
#pragma unroll
  for (int i = 0; i < NDB; ++i) d += Dpart[(size_t)r * NDB + i];
  invD[r] = 1.0f / d;
}

// ---------------- out[b,f] = trig_a * sum_t P*invD ----------------
__global__ __launch_bounds__(256) void k_final(const __half* __restrict__ P,
                                               const float* __restrict__ invD,
                                               const float* __restrict__ h,
                                               const float* __restrict__ x,
                                               const int* __restrict__ trig,
                                               float* __restrict__ out) {
  int b = blockIdx.x;
  int f = blockIdx.y * 256 + threadIdx.x;
  const __half* Pp = P + (size_t)b * NS * NF + f;
  const float*  iv = invD + b * NS;
  float acc = 0.f;
#pragma unroll 4
  for (int t = 0; t < NS; ++t) acc += __half2float(Pp[(size_t)t * NF]) * iv[t];
  int tr = trig[b];
  float ta = (f < KH) ? h[((size_t)b * NS + tr) * KH + f]
                      : x[((size_t)b * NS + tr) * SIN + f - KH];
  out[b * NF + f] = acc * ta;
}

extern "C" void kernel_launch(void* const* d_in, const int* in_sizes, int n_in,
                              void* d_out, int out_size, void* d_ws, size_t ws_size,
                              hipStream_t stream) {
  const float* h_state = (const float*)d_in[0];
  const float* x       = (const float*)d_in[1];
  const int*   trigger = (const int*)d_in[2];
  const int*   mask    = (const int*)d_in[3];
  const float* Wa      = (const float*)d_in[4];
  const float* ba      = (const float*)d_in[5];
  const float* Ws      = (const float*)d_in[6];
  const float* bs      = (const float*)d_in[7];
  float*       out     = (float*)d_out;

  // workspace layout (bytes), total ~224 MB
  char* w = (char*)d_ws;
  u16*    Abf   = (u16*)w;                 w += (size_t)NM * NF * 2;    // 100663296
  u16*    WaT   = (u16*)w;                 w += (size_t)NF * NF * 2;    //  18874368
  __half* P     = (__half*)w;              w += (size_t)NM * NF * 2;    // 100663296
  float*  s     = (float*)w;               w += (size_t)NBAT * KH * 4;  //    262144
  float*  base  = (float*)w;               w += (size_t)NBAT * NF * 4;  //    393216
  float*  Dpart = (float*)w;               w += (size_t)NM * NDB * 4;   //   3145728
  float*  invD  = (float*)w;               w += (size_t)NM * 4;         //     65536

  (void)in_sizes; (void)n_in; (void)out_size; (void)ws_size;

  k_sum_h <<<dim3(NBAT, KH / 256), 256, 0, stream>>>(h_state, s);
  k_cvt_a <<<dim3(NM * (NF / 4) / 256), 256, 0, stream>>>(h_state, x, Abf);
  k_wat   <<<dim3(NF / 64, NF / 64), 256, 0, stream>>>(Wa, WaT);
  k_base  <<<dim3(NBAT, NF / 256), 256, 0, stream>>>(s, Ws, ba, bs, base);
  k_gemm  <<<dim3(NF / 128, NM / 128), 256, 0, stream>>>(Abf, WaT, base, mask, P, Dpart);
  k_invd  <<<dim3(NM / 256), 256, 0, stream>>>(Dpart, invD);
  k_final <<<dim3(NBAT, NF / 256), 256, 0, stream>>>(P, invD, h_state, x, trigger, out);
}

// Round 2
// 866.874 us; speedup vs baseline: 1.0513x; 1.0513x over previous
//
#include <hip/hip_runtime.h>
#include <hip/hip_bf16.h>
#include <hip/hip_fp16.h>

// Decoder_22273700397282 on MI355X (gfx950)
// out[b,f] = trigger_a[b,f] * sum_t softmax_f(tanh(a@Wa + ba + s@Ws + bs))[t,f]
// with mask==0 rows -> uniform 1/3072 (all-(-1e9) row).
//
// R1 change: XOR bank-conflict swizzle on the GEMM LDS tiles.
//  - global_load_lds writes linearly (wave-uniform base + lane*16B), so the
//    swizzle is applied by permuting the per-lane GLOBAL source column
//    (colbyte = ib ^ ((row&7)<<4)) and applying the same XOR on ds_read.
//    (guide rule #21: both-sides-or-neither)

namespace {
constexpr int SIN  = 1024;            // IN_SIZE
constexpr int KH   = 2048;            // 2*IN (h_state feature dim)
constexpr int NF   = 3072;            // 3*IN = OUT_SIZE = GEMM K and N
constexpr int NBAT = 32;              // B
constexpr int NS   = 512;             // S
constexpr int NM   = NBAT * NS;       // 16384 GEMM rows
constexpr int NDB  = NF / 64;         // 48 Dpart column blocks
}

typedef unsigned short u16;
typedef __bf16 bf16x8 __attribute__((ext_vector_type(8)));
typedef float  f32x4  __attribute__((ext_vector_type(4)));

#define ASYNC_CP16(gptr, lptr)                                                              \
  __builtin_amdgcn_global_load_lds((__attribute__((address_space(1))) void*)(gptr),         \
                                   (__attribute__((address_space(3))) void*)(lptr), 16, 0, 0)

__device__ __forceinline__ u16 f2b(float f) {
  union { float f; unsigned u; } v; v.f = f;
  unsigned u = v.u;
  u += 0x7FFFu + ((u >> 16) & 1u);     // round-to-nearest-even
  return (u16)(u >> 16);
}

// ---------------- s[b,k] = sum_t h[b,t,k] ----------------
__global__ __launch_bounds__(256) void k_sum_h(const float* __restrict__ h,
                                               float* __restrict__ s) {
  int b = blockIdx.x;
  int d = blockIdx.y * 256 + threadIdx.x;          // d < 2048
  const float* p = h + (size_t)b * NS * KH + d;
  float acc = 0.f;
#pragma unroll 8
  for (int t = 0; t < NS; ++t) acc += p[(size_t)t * KH];
  s[b * KH + d] = acc;
}

// ---------------- base[b,f] = s@Ws + ba + bs ----------------
__global__ __launch_bounds__(256) void k_base(const float* __restrict__ s,
                                              const float* __restrict__ Ws,
                                              const float* __restrict__ ba,
                                              const float* __restrict__ bs,
                                              float* __restrict__ base) {
  int b = blockIdx.x;
  int f = blockIdx.y * 256 + threadIdx.x;          // f < 3072
  const float* sb = s + b * KH;
  float acc = 0.f;
#pragma unroll 4
  for (int k = 0; k < KH; ++k) acc += sb[k] * Ws[(size_t)k * NF + f];
  base[b * NF + f] = acc + ba[f] + bs[f];
}

// ---------------- Abf[r,k] = bf16(concat(h,x)) ----------------
__global__ __launch_bounds__(256) void k_cvt_a(const float* __restrict__ h,
                                               const float* __restrict__ x,
                                               u16* __restrict__ A) {
  int tid = blockIdx.x * 256 + threadIdx.x;        // over NM * (NF/4)
  int r = tid / (NF / 4);
  int k = (tid - r * (NF / 4)) * 4;
  int b = r >> 9, t = r & 511;
  const float* src = (k < KH) ? h + ((size_t)b * NS + t) * KH + k
                              : x + ((size_t)b * NS + t) * SIN + (k - KH);
  float4 v = *(const float4*)src;
  ushort4 o;
  o.x = f2b(v.x); o.y = f2b(v.y); o.z = f2b(v.z); o.w = f2b(v.w);
  *(ushort4*)(A + (size_t)r * NF + k) = o;
}

// ---------------- WaT[f,k] = bf16(Wa[k,f]) ----------------
__global__ __launch_bounds__(256) void k_wat(const float* __restrict__ Wa,
                                             u16* __restrict__ WaT) {
  __shared__ float tile[64][65];
  int k0 = blockIdx.x * 64, f0 = blockIdx.y * 64;
  int tid = threadIdx.x;
  int col4 = (tid & 15) * 4, row = tid >> 4;       // 16 rows per pass
#pragma unroll
  for (int rr = 0; rr < 64; rr += 16) {
    float4 v = *(const float4*)(Wa + (size_t)(k0 + row + rr) * NF + f0 + col4);
    tile[row + rr][col4 + 0] = v.x; tile[row + rr][col4 + 1] = v.y;
    tile[row + rr][col4 + 2] = v.z; tile[row + rr][col4 + 3] = v.w;
  }
  __syncthreads();
#pragma unroll
  for (int rr = 0; rr < 64; rr += 16) {
    int f = f0 + row + rr;
    ushort4 o;
    o.x = f2b(tile[col4 + 0][row + rr]); o.y = f2b(tile[col4 + 1][row + rr]);
    o.z = f2b(tile[col4 + 2][row + rr]); o.w = f2b(tile[col4 + 3][row + rr]);
    *(ushort4*)(WaT + (size_t)f * NF + k0 + col4) = o;
  }
}

// ---------------- main GEMM + tanh/exp epilogue ----------------
// C[r,c] = Abf[r,:] @ WaT[c,:]^T ; 128x128 tile, BK=64, 4 waves (2x2), m97
// structure + XOR bank swizzle (LDS (row, ib_bytes) holds global column
// ib ^ ((row&7)<<4)).
__global__ __launch_bounds__(256) void k_gemm(const u16* __restrict__ A,
                                              const u16* __restrict__ Wt,
                                              const float* __restrict__ base,
                                              const int* __restrict__ mask,
                                              __half* __restrict__ P,
                                              float* __restrict__ Dpart) {
  __shared__ __align__(16) u16 Asm[128 * 64];
  __shared__ __align__(16) u16 Bsm[128 * 64];
  const int tid  = threadIdx.x;
  const int wid  = tid >> 6, lane = tid & 63;
  const int wr   = wid >> 1, wc = wid & 1;         // 2x2 wave grid, each 64x64
  const int g    = lane >> 4, lr = lane & 15;
  const int r0   = blockIdx.y * 128;               // M tile (16384/128 = 128)
  const int c0   = blockIdx.x * 128;               // N tile (3072/128 = 24)

  f32x4 acc[4][4] = {};

  for (int kt = 0; kt < NF; kt += 64) {
#pragma unroll
    for (int q = 0; q < 4; ++q) {
      int cidx = q * 256 + tid;                    // 16B chunk id, 0..1023
      int arow = cidx >> 3;                        // 0..127
      // pre-swizzled global source column (u16 units): linear LDS dest then
      // holds the swizzled layout; ds_read applies the same XOR.
      int akb  = ((cidx & 7) * 8) ^ ((arow & 7) << 3);
      const u16* ga = A  + (size_t)(r0 + arow) * NF + kt + akb;
      const u16* gb = Wt + (size_t)(c0 + arow) * NF + kt + akb;
      // wave-uniform LDS base; HW adds lane*16B
      ASYNC_CP16(ga, Asm + q * 2048 + wid * 512);
      ASYNC_CP16(gb, Bsm + q * 2048 + wid * 512);
    }
    __syncthreads();                               // compiler emits vmcnt(0) drain
#pragma unroll
    for (int kk = 0; kk < 64; kk += 32) {
      bf16x8 af[4], bf[4];
#pragma unroll
      for (int m = 0; m < 4; ++m) {
        int ra = wr * 64 + m * 16 + lr;
        af[m] = *(const bf16x8*)&Asm[ra * 64 + ((kk + g * 8) ^ ((ra & 7) << 3))];
      }
#pragma unroll
      for (int n = 0; n < 4; ++n) {
        int rb = wc * 64 + n * 16 + lr;
        bf[n] = *(const bf16x8*)&Bsm[rb * 64 + ((kk + g * 8) ^ ((rb & 7) << 3))];
      }
#pragma unroll
      for (int m = 0; m < 4; ++m)
#pragma unroll
        for (int n = 0; n < 4; ++n)
          acc[m][n] = __builtin_amdgcn_mfma_f32_16x16x32_bf16(af[m], bf[n], acc[m][n], 0, 0, 0);
    }
    __syncthreads();
  }

  // epilogue: z = acc + base[b,c]; P = mask ? exp(tanh(z)) : 1; Dpart rowsums
  const int b = r0 >> 9;                           // 512 % 128 == 0 -> uniform per block
  const int cbase = c0 + wc * 64;
  int   cc[4];
  float bse[4];
#pragma unroll
  for (int n = 0; n < 4; ++n) {
    cc[n]  = cbase + n * 16 + lr;
    bse[n] = base[b * NF + cc[n]];
  }
#pragma unroll
  for (int m = 0; m < 4; ++m) {
#pragma unroll
    for (int j = 0; j < 4; ++j) {
      int r  = r0 + wr * 64 + m * 16 + g * 4 + j;
      int t  = r & 511;
      int mk = mask[b * NS + t];
      float rs = 0.f;
#pragma unroll
      for (int n = 0; n < 4; ++n) {
        float p;
        if (mk) {
          float z  = acc[m][n][j] + bse[n];
          z        = fminf(fmaxf(z, -15.f), 15.f);
          float e2 = __expf(2.f * z);
          float th = (e2 - 1.f) / (e2 + 1.f);      // tanh(z)
          p        = __expf(th);
        } else {
          p = 1.0f;
        }
        P[(size_t)r * NF + cc[n]] = __float2half(p);
        rs += p;
      }
      // reduce rs across the 16 lanes sharing this row (lr dimension)
#pragma unroll
      for (int off = 1; off < 16; off <<= 1) rs += __shfl_xor(rs, off, 64);
      if (lr == 0) Dpart[(size_t)r * NDB + (cbase >> 6)] = rs;
    }
  }
}

// ---------------- invD[r] = 1 / sum_nb Dpart[r,nb] ----------------
__global__ __launch_bounds__(256) void k_invd(const float* __restrict__ Dpart,
                                              float* __restrict__ invD) {
  int r = blockIdx.x * 256 + threadIdx.x;
  float d = 0.f;
#pragma unroll
  for (int i = 0; i < NDB; ++i) d += Dpart[(size_t)r * NDB + i];
  invD[r] = 1.0f / d;
}

// ---------------- out[b,f] = trig_a * sum_t P*invD ----------------
__global__ __launch_bounds__(256) void k_final(const __half* __restrict__ P,
                                               const float* __restrict__ invD,
                                               const float* __restrict__ h,
                                               const float* __restrict__ x,
                                               const int* __restrict__ trig,
                                               float* __restrict__ out) {
  int b = blockIdx.x;
  int f = blockIdx.y * 256 + threadIdx.x;
  const __half* Pp = P + (size_t)b * NS * NF + f;
  const float*  iv = invD + b * NS;
  float acc = 0.f;
#pragma unroll 4
  for (int t = 0; t < NS; ++t) acc += __half2float(Pp[(size_t)t * NF]) * iv[t];
  int tr = trig[b];
  float ta = (f < KH) ? h[((size_t)b * NS + tr) * KH + f]
                      : x[((size_t)b * NS + tr) * SIN + f - KH];
  out[b * NF + f] = acc * ta;
}

extern "C" void kernel_launch(void* const* d_in, const int* in_sizes, int n_in,
                              void* d_out, int out_size, void* d_ws, size_t ws_size,
                              hipStream_t stream) {
  const float* h_state = (const float*)d_in[0];
  const float* x       = (const float*)d_in[1];
  const int*   trigger = (const int*)d_in[2];
  const int*   mask    = (const int*)d_in[3];
  const float* Wa      = (const float*)d_in[4];
  const float* ba      = (const float*)d_in[5];
  const float* Ws      = (const float*)d_in[6];
  const float* bs      = (const float*)d_in[7];
  float*       out     = (float*)d_out;

  // workspace layout (bytes), total ~224 MB
  char* w = (char*)d_ws;
  u16*    Abf   = (u16*)w;                 w += (size_t)NM * NF * 2;    // 100663296
  u16*    WaT   = (u16*)w;                 w += (size_t)NF * NF * 2;    //  18874368
  __half* P     = (__half*)w;              w += (size_t)NM * NF * 2;    // 100663296
  float*  s     = (float*)w;               w += (size_t)NBAT * KH * 4;  //    262144
  float*  base  = (float*)w;               w += (size_t)NBAT * NF * 4;  //    393216
  float*  Dpart = (float*)w;               w += (size_t)NM * NDB * 4;   //   3145728
  float*  invD  = (float*)w;               w += (size_t)NM * 4;         //     65536

  (void)in_sizes; (void)n_in; (void)out_size; (void)ws_size;

  k_sum_h <<<dim3(NBAT, KH / 256), 256, 0, stream>>>(h_state, s);
  k_cvt_a <<<dim3(NM * (NF / 4) / 256), 256, 0, stream>>>(h_state, x, Abf);
  k_wat   <<<dim3(NF / 64, NF / 64), 256, 0, stream>>>(Wa, WaT);
  k_base  <<<dim3(NBAT, NF / 256), 256, 0, stream>>>(s, Ws, ba, bs, base);
  k_gemm  <<<dim3(NF / 128, NM / 128), 256, 0, stream>>>(Abf, WaT, base, mask, P, Dpart);
  k_invd  <<<dim3(NM / 256), 256, 0, stream>>>(Dpart, invD);
  k_final <<<dim3(NBAT, NF / 256), 256, 0, stream>>>(P, invD, h_state, x, trigger, out);
}

// Round 4
// 507.459 us; speedup vs baseline: 1.7958x; 1.7083x over previous
//
#include <hip/hip_runtime.h>
#include <hip/hip_bf16.h>
#include <hip/hip_fp16.h>

// Decoder_22273700397282 on MI355X (gfx950)
// out[b,f] = trigger_a[b,f] * sum_t softmax_f(tanh(a@Wa + ba + s@Ws + bs))[t,f]
// mask==0 rows -> softmax of uniform -1e9 row == exactly 1/3072 per feature.
//
// R3 fix: k_base1's LDS tile was declared [32][32] but indexed [32][256]
// (stray /8) -> LDS overflow -> garbage base. Now [NBAT][KH/KC] = 32 KB.
// R2 design: MASK COMPACTION — only mask==1 rows (~50%) run the bf16 GEMM;
// mask==0 rows contribute (512-cnt)/3072 analytically in the finalizer.

namespace {
constexpr int SIN  = 1024;            // IN_SIZE
constexpr int KH   = 2048;            // 2*IN (h_state feature dim)
constexpr int NF   = 3072;            // 3*IN = OUT_SIZE = GEMM K and N
constexpr int NBAT = 32;              // B
constexpr int NS   = 512;             // S
constexpr int NM   = NBAT * NS;       // 16384 worst-case GEMM rows
constexpr int NDB  = NF / 64;         // 48 Dpart column blocks
constexpr int KC   = 8;               // k-chunks for k_base1
}

typedef unsigned short u16;
typedef __bf16 bf16x8 __attribute__((ext_vector_type(8)));
typedef float  f32x4  __attribute__((ext_vector_type(4)));

#define ASYNC_CP16(gptr, lptr)                                                              \
  __builtin_amdgcn_global_load_lds((__attribute__((address_space(1))) void*)(gptr),         \
                                   (__attribute__((address_space(3))) void*)(lptr), 16, 0, 0)

__device__ __forceinline__ u16 f2b(float f) {
  union { float f; unsigned u; } v; v.f = f;
  unsigned u = v.u;
  u += 0x7FFFu + ((u >> 16) & 1u);     // round-to-nearest-even
  return (u16)(u >> 16);
}

// ---------------- compaction: counts ----------------
__global__ __launch_bounds__(64) void k_cnt(const int* __restrict__ mask,
                                            int* __restrict__ bcnt) {
  int b = blockIdx.x, t = threadIdx.x;
  int c = 0;
#pragma unroll
  for (int i = 0; i < NS / 64; ++i) c += mask[b * NS + i * 64 + t];
#pragma unroll
  for (int off = 32; off >= 1; off >>= 1) c += __shfl_down(c, off, 64);
  if (t == 0) bcnt[b] = c;
}

// ---------------- compaction: scan (serial, 32 entries) ----------------
__global__ __launch_bounds__(64) void k_scan(const int* __restrict__ bcnt,
                                             int* __restrict__ boff,
                                             int* __restrict__ meta) {
  if (threadIdx.x == 0) {
    int run = 0;
    for (int b = 0; b < NBAT; ++b) { boff[b] = run; run += bcnt[b]; }
    meta[0] = run;                       // Mc
    meta[1] = (run + 127) & ~127;        // McPad (128-row tiles)
  }
}

// ---------------- compaction: gather ----------------
__global__ __launch_bounds__(512) void k_gather(const int* __restrict__ mask,
                                                const int* __restrict__ boff,
                                                const int* __restrict__ meta,
                                                int* __restrict__ rowmap) {
  __shared__ int ps[NS];
  int b = blockIdx.x, t = threadIdx.x;
  int m = mask[b * NS + t];
  ps[t] = m;
  __syncthreads();
#pragma unroll
  for (int off = 1; off < NS; off <<= 1) {
    int v = (t >= off) ? ps[t - off] : 0;
    __syncthreads();
    ps[t] += v;
    __syncthreads();
  }
  if (m) rowmap[boff[b] + ps[t] - m] = b * NS + t;
  if (b == 0 && t < 128) {               // zero-pad rowmap up to McPad
    int Mc = meta[0], McPad = meta[1];
    if (Mc + t < McPad) rowmap[Mc + t] = 0;
  }
}

// ---------------- s[b,k] = sum_t h[b,t,k] ----------------
__global__ __launch_bounds__(256) void k_sum_h(const float* __restrict__ h,
                                               float* __restrict__ s) {
  int b = blockIdx.x;
  int d = blockIdx.y * 256 + threadIdx.x;          // d < 2048
  const float* p = h + (size_t)b * NS * KH + d;
  float acc = 0.f;
#pragma unroll 8
  for (int t = 0; t < NS; ++t) acc += p[(size_t)t * KH];
  s[b * KH + d] = acc;
}

// ---------------- base partials: reads Ws once ----------------
__global__ __launch_bounds__(256) void k_base1(const float* __restrict__ s,
                                               const float* __restrict__ Ws,
                                               float* __restrict__ basep) {
  __shared__ float sT[NBAT][KH / KC];      // [32][256] = 32 KB
  int f  = blockIdx.x * 256 + threadIdx.x;
  int k0 = blockIdx.y * (KH / KC);          // 256-wide k slice
  // cooperative load of s[:, k0:k0+256]
  for (int it = 0; it < NBAT; ++it) {
    int idx = it * 256 + threadIdx.x;
    int b = idx >> 8, kk = idx & 255;
    sT[b][kk] = s[b * KH + k0 + kk];
  }
  __syncthreads();
  float acc[NBAT] = {};
  for (int k = 0; k < KH / KC; ++k) {
    float w = Ws[(size_t)(k0 + k) * NF + f];
#pragma unroll
    for (int b = 0; b < NBAT; ++b) acc[b] += sT[b][k] * w;
  }
#pragma unroll
  for (int b = 0; b < NBAT; ++b)
    basep[((size_t)blockIdx.y * NBAT + b) * NF + f] = acc[b];
}

__global__ __launch_bounds__(256) void k_base2(const float* __restrict__ basep,
                                               const float* __restrict__ ba,
                                               const float* __restrict__ bs,
                                               float* __restrict__ base) {
  int b = blockIdx.x;
  int f = blockIdx.y * 256 + threadIdx.x;
  float acc = 0.f;
#pragma unroll
  for (int kc = 0; kc < KC; ++kc) acc += basep[((size_t)kc * NBAT + b) * NF + f];
  base[b * NF + f] = acc + ba[f] + bs[f];
}

// ---------------- Abf[i,k] = bf16(concat(h,x)[rowmap[i],k]) ----------------
__global__ __launch_bounds__(256) void k_cvt_a(const float* __restrict__ h,
                                               const float* __restrict__ x,
                                               const int* __restrict__ rowmap,
                                               const int* __restrict__ meta,
                                               u16* __restrict__ A) {
  int tid = blockIdx.x * 256 + threadIdx.x;        // over NM * (NF/4)
  int i = tid / (NF / 4);
  if (i >= meta[1]) return;                        // beyond McPad
  int k = (tid - i * (NF / 4)) * 4;
  ushort4 o;
  if (i >= meta[0]) {                              // zero-pad rows [Mc, McPad)
    o.x = o.y = o.z = o.w = 0;
  } else {
    int ro = rowmap[i];
    int b = ro >> 9, t = ro & 511;
    const float* src = (k < KH) ? h + ((size_t)b * NS + t) * KH + k
                                : x + ((size_t)b * NS + t) * SIN + (k - KH);
    float4 v = *(const float4*)src;
    o.x = f2b(v.x); o.y = f2b(v.y); o.z = f2b(v.z); o.w = f2b(v.w);
  }
  *(ushort4*)(A + (size_t)i * NF + k) = o;
}

// ---------------- WaT[f,k] = bf16(Wa[k,f]) ----------------
__global__ __launch_bounds__(256) void k_wat(const float* __restrict__ Wa,
                                             u16* __restrict__ WaT) {
  __shared__ float tile[64][65];
  int k0 = blockIdx.x * 64, f0 = blockIdx.y * 64;
  int tid = threadIdx.x;
  int col4 = (tid & 15) * 4, row = tid >> 4;       // 16 rows per pass
#pragma unroll
  for (int rr = 0; rr < 64; rr += 16) {
    float4 v = *(const float4*)(Wa + (size_t)(k0 + row + rr) * NF + f0 + col4);
    tile[row + rr][col4 + 0] = v.x; tile[row + rr][col4 + 1] = v.y;
    tile[row + rr][col4 + 2] = v.z; tile[row + rr][col4 + 3] = v.w;
  }
  __syncthreads();
#pragma unroll
  for (int rr = 0; rr < 64; rr += 16) {
    int f = f0 + row + rr;
    ushort4 o;
    o.x = f2b(tile[col4 + 0][row + rr]); o.y = f2b(tile[col4 + 1][row + rr]);
    o.z = f2b(tile[col4 + 2][row + rr]); o.w = f2b(tile[col4 + 3][row + rr]);
    *(ushort4*)(WaT + (size_t)f * NF + k0 + col4) = o;
  }
}

// ---------------- main GEMM + tanh/exp epilogue (compacted rows) ----------
// 128x128 tile, BK=64, 4 waves (2x2), m97 structure + XOR bank swizzle.
__global__ __launch_bounds__(256) void k_gemm(const u16* __restrict__ A,
                                              const u16* __restrict__ Wt,
                                              const float* __restrict__ base,
                                              const int* __restrict__ rowmap,
                                              const int* __restrict__ meta,
                                              __half* __restrict__ P,
                                              float* __restrict__ Dpart) {
  __shared__ __align__(16) u16 Asm[128 * 64];
  __shared__ __align__(16) u16 Bsm[128 * 64];
  const int r0 = blockIdx.y * 128;                 // compacted M tile
  if (r0 >= meta[1]) return;                       // beyond McPad: no work
  const int tid  = threadIdx.x;
  const int wid  = tid >> 6, lane = tid & 63;
  const int wr   = wid >> 1, wc = wid & 1;         // 2x2 wave grid, each 64x64
  const int g    = lane >> 4, lr = lane & 15;
  const int c0   = blockIdx.x * 128;               // N tile (3072/128 = 24)

  f32x4 acc[4][4] = {};

  for (int kt = 0; kt < NF; kt += 64) {
#pragma unroll
    for (int q = 0; q < 4; ++q) {
      int cidx = q * 256 + tid;                    // 16B chunk id, 0..1023
      int arow = cidx >> 3;                        // 0..127
      // pre-swizzled global source column (u16 units): linear LDS dest then
      // holds the swizzled layout; ds_read applies the same XOR.
      int akb  = ((cidx & 7) * 8) ^ ((arow & 7) << 3);
      const u16* ga = A  + (size_t)(r0 + arow) * NF + kt + akb;
      const u16* gb = Wt + (size_t)(c0 + arow) * NF + kt + akb;
      // wave-uniform LDS base; HW adds lane*16B
      ASYNC_CP16(ga, Asm + q * 2048 + wid * 512);
      ASYNC_CP16(gb, Bsm + q * 2048 + wid * 512);
    }
    __syncthreads();                               // compiler emits vmcnt(0) drain
#pragma unroll
    for (int kk = 0; kk < 64; kk += 32) {
      bf16x8 af[4], bf[4];
#pragma unroll
      for (int m = 0; m < 4; ++m) {
        int ra = wr * 64 + m * 16 + lr;
        af[m] = *(const bf16x8*)&Asm[ra * 64 + ((kk + g * 8) ^ ((ra & 7) << 3))];
      }
#pragma unroll
      for (int n = 0; n < 4; ++n) {
        int rb = wc * 64 + n * 16 + lr;
        bf[n] = *(const bf16x8*)&Bsm[rb * 64 + ((kk + g * 8) ^ ((rb & 7) << 3))];
      }
#pragma unroll
      for (int m = 0; m < 4; ++m)
#pragma unroll
        for (int n = 0; n < 4; ++n)
          acc[m][n] = __builtin_amdgcn_mfma_f32_16x16x32_bf16(af[m], bf[n], acc[m][n], 0, 0, 0);
    }
    __syncthreads();
  }

  // epilogue: z = acc + base[b(row),c]; P = exp(tanh(z)); Dpart rowsums.
  // All compacted rows have mask==1; padded rows produce trash never read.
  const int cbase = c0 + wc * 64;
  int cc[4];
#pragma unroll
  for (int n = 0; n < 4; ++n) cc[n] = cbase + n * 16 + lr;
#pragma unroll
  for (int m = 0; m < 4; ++m) {
#pragma unroll
    for (int j = 0; j < 4; ++j) {
      int i  = r0 + wr * 64 + m * 16 + g * 4 + j;  // compacted row
      int b  = rowmap[i] >> 9;                     // original batch
      float rs = 0.f;
#pragma unroll
      for (int n = 0; n < 4; ++n) {
        float z  = acc[m][n][j] + base[b * NF + cc[n]];
        z        = fminf(fmaxf(z, -15.f), 15.f);
        float e2 = __expf(2.f * z);
        float th = (e2 - 1.f) / (e2 + 1.f);        // tanh(z)
        float p  = __expf(th);
        P[(size_t)i * NF + cc[n]] = __float2half(p);
        rs += p;
      }
#pragma unroll
      for (int off = 1; off < 16; off <<= 1) rs += __shfl_xor(rs, off, 64);
      if (lr == 0) Dpart[(size_t)i * NDB + (cbase >> 6)] = rs;
    }
  }
}

// ---------------- invD[i] = 1 / sum_nb Dpart[i,nb] ----------------
__global__ __launch_bounds__(256) void k_invd(const float* __restrict__ Dpart,
                                              const int* __restrict__ meta,
                                              float* __restrict__ invD) {
  int i = blockIdx.x * 256 + threadIdx.x;
  if (i >= meta[1]) return;
  float d = 0.f;
#pragma unroll
  for (int q = 0; q < NDB; ++q) d += Dpart[(size_t)i * NDB + q];
  invD[i] = 1.0f / d;
}

// ---------------- out[b,f] = trig_a * (sum_i P*invD + (512-cnt)/3072) -----
__global__ __launch_bounds__(256) void k_final(const __half* __restrict__ P,
                                               const float* __restrict__ invD,
                                               const int* __restrict__ boff,
                                               const int* __restrict__ bcnt,
                                               const float* __restrict__ h,
                                               const float* __restrict__ x,
                                               const int* __restrict__ trig,
                                               float* __restrict__ out) {
  int b = blockIdx.x;
  int f = blockIdx.y * 256 + threadIdx.x;
  int off = boff[b], cnt = bcnt[b];
  const __half* Pp = P + (size_t)off * NF + f;
  const float*  iv = invD + off;
  float acc = 0.f;
  for (int t = 0; t < cnt; ++t) acc += __half2float(Pp[(size_t)t * NF]) * iv[t];
  acc += (float)(NS - cnt) * (1.0f / (float)NF);   // uniform masked rows
  int tr = trig[b];
  float ta = (f < KH) ? h[((size_t)b * NS + tr) * KH + f]
                      : x[((size_t)b * NS + tr) * SIN + f - KH];
  out[b * NF + f] = acc * ta;
}

extern "C" void kernel_launch(void* const* d_in, const int* in_sizes, int n_in,
                              void* d_out, int out_size, void* d_ws, size_t ws_size,
                              hipStream_t stream) {
  const float* h_state = (const float*)d_in[0];
  const float* x       = (const float*)d_in[1];
  const int*   trigger = (const int*)d_in[2];
  const int*   mask    = (const int*)d_in[3];
  const float* Wa      = (const float*)d_in[4];
  const float* ba      = (const float*)d_in[5];
  const float* Ws      = (const float*)d_in[6];
  const float* bs      = (const float*)d_in[7];
  float*       out     = (float*)d_out;

  // workspace layout (bytes), total ~224 MB
  char* w = (char*)d_ws;
  u16*    Abf   = (u16*)w;                 w += (size_t)NM * NF * 2;    // 100663296
  u16*    WaT   = (u16*)w;                 w += (size_t)NF * NF * 2;    //  18874368
  __half* P     = (__half*)w;              w += (size_t)NM * NF * 2;    // 100663296
  float*  s     = (float*)w;               w += (size_t)NBAT * KH * 4;  //    262144
  float*  base  = (float*)w;               w += (size_t)NBAT * NF * 4;  //    393216
  float*  Dpart = (float*)w;               w += (size_t)NM * NDB * 4;   //   3145728
  float*  basep = (float*)Dpart;           // KC*NBAT*NF*4 = 3145728, aliases Dpart
                                           // (WAR: k_base2 reads before k_gemm writes)
  float*  invD  = (float*)w;               w += (size_t)NM * 4;         //     65536
  int*    rowmap= (int*)w;                 w += (size_t)NM * 4;         //     65536
  int*    bcnt  = (int*)w;                 w += 128;
  int*    boff  = (int*)w;                 w += 128;
  int*    meta  = (int*)w;                 w += 128;

  (void)in_sizes; (void)n_in; (void)out_size; (void)ws_size;

  k_cnt   <<<dim3(NBAT), 64, 0, stream>>>(mask, bcnt);
  k_scan  <<<dim3(1), 64, 0, stream>>>(bcnt, boff, meta);
  k_gather<<<dim3(NBAT), 512, 0, stream>>>(mask, boff, meta, rowmap);
  k_sum_h <<<dim3(NBAT, KH / 256), 256, 0, stream>>>(h_state, s);
  k_cvt_a <<<dim3(NM * (NF / 4) / 256), 256, 0, stream>>>(h_state, x, rowmap, meta, Abf);
  k_wat   <<<dim3(NF / 64, NF / 64), 256, 0, stream>>>(Wa, WaT);
  k_base1 <<<dim3(NF / 256, KC), 256, 0, stream>>>(s, Ws, basep);
  k_base2 <<<dim3(NBAT, NF / 256), 256, 0, stream>>>(basep, ba, bs, base);
  k_gemm  <<<dim3(NF / 128, NM / 128), 256, 0, stream>>>(Abf, WaT, base, rowmap, meta, P, Dpart);
  k_invd  <<<dim3(NM / 256), 256, 0, stream>>>(Dpart, meta, invD);
  k_final <<<dim3(NBAT, NF / 256), 256, 0, stream>>>(P, invD, boff, bcnt, h_state, x, trigger, out);
}

// Round 5
// 464.800 us; speedup vs baseline: 1.9607x; 1.0918x over previous
//
#include <hip/hip_runtime.h>
#include <hip/hip_bf16.h>
#include <hip/hip_fp16.h>

// Decoder_22273700397282 on MI355X (gfx950)
// out[b,f] = trigger_a[b,f] * sum_t softmax_f(tanh(a@Wa + ba + s@Ws + bs))[t,f]
// mask==0 rows -> exactly 1/3072 per feature (handled analytically).
//
// R4: k_gemm rebuilt as 256x256-tile 8-phase schedule (T2 swizzle + T3/T4
// counted vmcnt(4) + T5 setprio + T1 bijective XCD swizzle over active
// blocks). Half-tile = K-half (256x32) so staging granularity matches the
// phase schedule; per-subtile chunk XOR swizzle keeps ds_read_b128 at 2-way
// (free). k_final vectorized to 16B loads.

namespace {
constexpr int SIN  = 1024;            // IN_SIZE
constexpr int KH   = 2048;            // 2*IN
constexpr int NF   = 3072;            // 3*IN = GEMM K and N
constexpr int NBAT = 32;
constexpr int NS   = 512;
constexpr int NM   = NBAT * NS;       // 16384 worst-case GEMM rows
constexpr int NDB  = NF / 64;         // 48 Dpart column blocks
constexpr int KC   = 8;               // k-chunks for k_base1
constexpr int NKT  = NF / 64;         // 48 K-tiles of 64
}

typedef unsigned short u16;
typedef __bf16 bf16x8 __attribute__((ext_vector_type(8)));
typedef float  f32x4  __attribute__((ext_vector_type(4)));

#define ASYNC_CP16(gptr, lptr)                                                              \
  __builtin_amdgcn_global_load_lds((__attribute__((address_space(1))) void*)(gptr),         \
                                   (__attribute__((address_space(3))) void*)(lptr), 16, 0, 0)

__device__ __forceinline__ u16 f2b(float f) {
  union { float f; unsigned u; } v; v.f = f;
  unsigned u = v.u;
  u += 0x7FFFu + ((u >> 16) & 1u);     // round-to-nearest-even
  return (u16)(u >> 16);
}

// ---------------- compaction: counts ----------------
__global__ __launch_bounds__(64) void k_cnt(const int* __restrict__ mask,
                                            int* __restrict__ bcnt) {
  int b = blockIdx.x, t = threadIdx.x;
  int c = 0;
#pragma unroll
  for (int i = 0; i < NS / 64; ++i) c += mask[b * NS + i * 64 + t];
#pragma unroll
  for (int off = 32; off >= 1; off >>= 1) c += __shfl_down(c, off, 64);
  if (t == 0) bcnt[b] = c;
}

// ---------------- compaction: scan ----------------
__global__ __launch_bounds__(64) void k_scan(const int* __restrict__ bcnt,
                                             int* __restrict__ boff,
                                             int* __restrict__ meta) {
  if (threadIdx.x == 0) {
    int run = 0;
    for (int b = 0; b < NBAT; ++b) { boff[b] = run; run += bcnt[b]; }
    meta[0] = run;                       // Mc
    meta[1] = (run + 255) & ~255;        // McPad (256-row tiles)
  }
}

// ---------------- compaction: gather ----------------
__global__ __launch_bounds__(512) void k_gather(const int* __restrict__ mask,
                                                const int* __restrict__ boff,
                                                const int* __restrict__ meta,
                                                int* __restrict__ rowmap) {
  __shared__ int ps[NS];
  int b = blockIdx.x, t = threadIdx.x;
  int m = mask[b * NS + t];
  ps[t] = m;
  __syncthreads();
#pragma unroll
  for (int off = 1; off < NS; off <<= 1) {
    int v = (t >= off) ? ps[t - off] : 0;
    __syncthreads();
    ps[t] += v;
    __syncthreads();
  }
  if (m) rowmap[boff[b] + ps[t] - m] = b * NS + t;
  if (b == 0) {                          // zero-pad rowmap up to McPad
    int Mc = meta[0], McPad = meta[1];
    if (Mc + t < McPad) rowmap[Mc + t] = 0;
  }
}

// ---------------- s[b,k] = sum_t h[b,t,k] ----------------
__global__ __launch_bounds__(256) void k_sum_h(const float* __restrict__ h,
                                               float* __restrict__ s) {
  int b = blockIdx.x;
  int d = blockIdx.y * 256 + threadIdx.x;
  const float* p = h + (size_t)b * NS * KH + d;
  float acc = 0.f;
#pragma unroll 8
  for (int t = 0; t < NS; ++t) acc += p[(size_t)t * KH];
  s[b * KH + d] = acc;
}

// ---------------- base partials: reads Ws once ----------------
__global__ __launch_bounds__(256) void k_base1(const float* __restrict__ s,
                                               const float* __restrict__ Ws,
                                               float* __restrict__ basep) {
  __shared__ float sT[NBAT][KH / KC];      // [32][256] = 32 KB
  int f  = blockIdx.x * 256 + threadIdx.x;
  int k0 = blockIdx.y * (KH / KC);
  for (int it = 0; it < NBAT; ++it) {
    int idx = it * 256 + threadIdx.x;
    int b = idx >> 8, kk = idx & 255;
    sT[b][kk] = s[b * KH + k0 + kk];
  }
  __syncthreads();
  float acc[NBAT] = {};
  for (int k = 0; k < KH / KC; ++k) {
    float w = Ws[(size_t)(k0 + k) * NF + f];
#pragma unroll
    for (int b = 0; b < NBAT; ++b) acc[b] += sT[b][k] * w;
  }
#pragma unroll
  for (int b = 0; b < NBAT; ++b)
    basep[((size_t)blockIdx.y * NBAT + b) * NF + f] = acc[b];
}

__global__ __launch_bounds__(256) void k_base2(const float* __restrict__ basep,
                                               const float* __restrict__ ba,
                                               const float* __restrict__ bs,
                                               float* __restrict__ base) {
  int b = blockIdx.x;
  int f = blockIdx.y * 256 + threadIdx.x;
  float acc = 0.f;
#pragma unroll
  for (int kc = 0; kc < KC; ++kc) acc += basep[((size_t)kc * NBAT + b) * NF + f];
  base[b * NF + f] = acc + ba[f] + bs[f];
}

// ---------------- Abf[i,k] = bf16(concat(h,x)[rowmap[i],k]) ----------------
__global__ __launch_bounds__(256) void k_cvt_a(const float* __restrict__ h,
                                               const float* __restrict__ x,
                                               const int* __restrict__ rowmap,
                                               const int* __restrict__ meta,
                                               u16* __restrict__ A) {
  int tid = blockIdx.x * 256 + threadIdx.x;
  int i = tid / (NF / 4);
  if (i >= meta[1]) return;
  int k = (tid - i * (NF / 4)) * 4;
  ushort4 o;
  if (i >= meta[0]) {
    o.x = o.y = o.z = o.w = 0;
  } else {
    int ro = rowmap[i];
    int b = ro >> 9, t = ro & 511;
    const float* src = (k < KH) ? h + ((size_t)b * NS + t) * KH + k
                                : x + ((size_t)b * NS + t) * SIN + (k - KH);
    float4 v = *(const float4*)src;
    o.x = f2b(v.x); o.y = f2b(v.y); o.z = f2b(v.z); o.w = f2b(v.w);
  }
  *(ushort4*)(A + (size_t)i * NF + k) = o;
}

// ---------------- WaT[f,k] = bf16(Wa[k,f]) ----------------
__global__ __launch_bounds__(256) void k_wat(const float* __restrict__ Wa,
                                             u16* __restrict__ WaT) {
  __shared__ float tile[64][65];
  int k0 = blockIdx.x * 64, f0 = blockIdx.y * 64;
  int tid = threadIdx.x;
  int col4 = (tid & 15) * 4, row = tid >> 4;
#pragma unroll
  for (int rr = 0; rr < 64; rr += 16) {
    float4 v = *(const float4*)(Wa + (size_t)(k0 + row + rr) * NF + f0 + col4);
    tile[row + rr][col4 + 0] = v.x; tile[row + rr][col4 + 1] = v.y;
    tile[row + rr][col4 + 2] = v.z; tile[row + rr][col4 + 3] = v.w;
  }
  __syncthreads();
#pragma unroll
  for (int rr = 0; rr < 64; rr += 16) {
    int f = f0 + row + rr;
    ushort4 o;
    o.x = f2b(tile[col4 + 0][row + rr]); o.y = f2b(tile[col4 + 1][row + rr]);
    o.z = f2b(tile[col4 + 2][row + rr]); o.w = f2b(tile[col4 + 3][row + rr]);
    *(ushort4*)(WaT + (size_t)f * NF + k0 + col4) = o;
  }
}

// ---------------- main GEMM: 256x256 tile, 8-phase schedule ----------------
// lds[buf][mat][khalf]: [256][32] u16 subtile, chunk-XOR swizzled.
// Element (row, kc) stored at row*32 + (kc ^ (((row>>1)&3)<<3)).
#define LDSOFF(row, gg) ((row) * 32 + ((((gg) ^ (((row) >> 1) & 3))) << 3))

#define LDB4(BUF, KS)                                                        \
  _Pragma("unroll") for (int nf = 0; nf < 4; ++nf) {                         \
    int rb = wc * 64 + nf * 16 + lr;                                         \
    bfr[nf] = *(const bf16x8*)&lds[BUF][1][KS][LDSOFF(rb, g)];               \
  }

#define LDA4(BUF, KS, MH)                                                    \
  _Pragma("unroll") for (int mf = 0; mf < 4; ++mf) {                         \
    int ra = wr * 128 + ((MH) * 4 + mf) * 16 + lr;                           \
    afr[mf] = *(const bf16x8*)&lds[BUF][0][KS][LDSOFF(ra, g)];               \
  }

#define MFMA16(MH)                                                           \
  _Pragma("unroll") for (int mf = 0; mf < 4; ++mf)                           \
  _Pragma("unroll") for (int nf = 0; nf < 4; ++nf)                           \
    acc[(MH) * 4 + mf][nf] = __builtin_amdgcn_mfma_f32_16x16x32_bf16(        \
        afr[mf], bfr[nf], acc[(MH) * 4 + mf][nf], 0, 0, 0);

// stage one K-half subtile (256x32 = 16 KB = 2 issues of 8 KB)
#define STAGE(SMAT, SBUF, SKS, SKT)                                          \
  if ((SKT) < NKT) {                                                         \
    _Pragma("unroll") for (int q = 0; q < 2; ++q) {                          \
      const u16* src = ((SMAT) ? pB[q] : pA[q]) + (SKT) * 64 + (SKS) * 32;   \
      ASYNC_CP16(src, &lds[SBUF][SMAT][SKS][q * 4096 + wid * 512]);          \
    }                                                                        \
  }

#define PH(BUF, KS, MH, SMAT, SBUF, SKS, SKT, VM)                            \
  {                                                                          \
    if ((MH) == 0) { LDB4(BUF, KS) }                                         \
    LDA4(BUF, KS, MH)                                                        \
    STAGE(SMAT, SBUF, SKS, SKT)                                              \
    __builtin_amdgcn_s_barrier();                                            \
    asm volatile("s_waitcnt lgkmcnt(0)" ::: "memory");                       \
    __builtin_amdgcn_s_setprio(1);                                           \
    MFMA16(MH)                                                               \
    __builtin_amdgcn_s_setprio(0);                                           \
    if (VM) asm volatile("s_waitcnt vmcnt(4)" ::: "memory");                 \
    __builtin_amdgcn_s_barrier();                                            \
  }

__global__ __launch_bounds__(512, 2) void k_gemm(const u16* __restrict__ A,
                                                 const u16* __restrict__ Wt,
                                                 const float* __restrict__ base,
                                                 const int* __restrict__ rowmap,
                                                 const int* __restrict__ meta,
                                                 __half* __restrict__ P,
                                                 float* __restrict__ Dpart) {
  __shared__ __align__(16) u16 lds[2][2][2][8192];   // 128 KB
  const int MT   = meta[1] >> 8;                      // active M-tiles
  const int nact = MT * 12;
  const int flat = blockIdx.x;
  if (flat >= nact) return;
  // bijective XCD-chunked swizzle over the active blocks (ERRATA #11 form)
  const int qx = nact >> 3, rx = nact & 7;
  const int xcd = flat & 7, idx = flat >> 3;
  const int swz = (xcd < rx) ? xcd * (qx + 1) + idx
                             : rx * (qx + 1) + (xcd - rx) * qx + idx;
  const int mt = swz / 12, nt = swz - mt * 12;        // n fastest: A-panel L2 reuse
  const int r0 = mt << 8, c0 = nt << 8;

  const int tid = threadIdx.x;
  const int wid = tid >> 6, lane = tid & 63;
  const int wr = wid >> 2, wc = wid & 3;              // 2M x 4N waves, 128x64 each
  const int g = lane >> 4, lr = lane & 15;

  // per-lane staging source pointers (swizzle folded into source column)
  const u16* pA[2]; const u16* pB[2];
#pragma unroll
  for (int q = 0; q < 2; ++q) {
    int c = q * 512 + tid;
    int row = c >> 2;
    int kc8 = (((c & 3) ^ ((row >> 1) & 3)) << 3);
    pA[q] = A  + (size_t)(r0 + row) * NF + kc8;
    pB[q] = Wt + (size_t)(c0 + row) * NF + kc8;
  }

  f32x4 acc[8][4] = {};
  bf16x8 afr[4], bfr[4];

  // prologue: kt0 complete + kt1 K-half0 (12 issues); drain kt0 (leave 4)
  STAGE(0, 0, 0, 0) STAGE(1, 0, 0, 0)
  STAGE(0, 0, 1, 0) STAGE(1, 0, 1, 0)
  STAGE(0, 1, 0, 1) STAGE(1, 1, 0, 1)
  asm volatile("s_waitcnt vmcnt(4)" ::: "memory");
  __builtin_amdgcn_s_barrier();

  // main loop: iteration computes kt=2i (buf0) and kt=2i+1 (buf1).
  // Slot schedule (stage >=1 barrier after last read, lands >=4 phases early):
  //  ph1: A-ks1(kt2i+1)->b1  ph2: B-ks1(kt2i+1)->b1
  //  ph3: A-ks0(kt2i+2)->b0  ph4: B-ks0(kt2i+2)->b0  + vmcnt(4)
  //  ph5: A-ks1(kt2i+2)->b0  ph6: B-ks1(kt2i+2)->b0
  //  ph7: A-ks0(kt2i+3)->b1  ph8: B-ks0(kt2i+3)->b1  + vmcnt(4)
#pragma unroll 1
  for (int i = 0; i < NKT / 2; ++i) {
    const int kt1 = 2 * i + 1, kt2 = 2 * i + 2, kt3 = 2 * i + 3;
    PH(0, 0, 0, 0, 1, 1, kt1, 0)
    PH(0, 0, 1, 1, 1, 1, kt1, 0)
    PH(0, 1, 0, 0, 0, 0, kt2, 0)
    PH(0, 1, 1, 1, 0, 0, kt2, 1)
    PH(1, 0, 0, 0, 0, 1, kt2, 0)
    PH(1, 0, 1, 1, 0, 1, kt2, 0)
    PH(1, 1, 0, 0, 1, 0, kt3, 0)
    PH(1, 1, 1, 1, 1, 0, kt3, 1)
  }

  // epilogue: z = acc + base; P = exp(tanh(z)); Dpart rowsums
  const int cbase = c0 + wc * 64;
#pragma unroll
  for (int mf = 0; mf < 8; ++mf) {
#pragma unroll
    for (int j = 0; j < 4; ++j) {
      int i = r0 + wr * 128 + mf * 16 + g * 4 + j;   // compacted row
      int b = rowmap[i] >> 9;                        // original batch
      float rs = 0.f;
#pragma unroll
      for (int nf = 0; nf < 4; ++nf) {
        int ccn = cbase + nf * 16 + lr;
        float z  = acc[mf][nf][j] + base[b * NF + ccn];
        z        = fminf(fmaxf(z, -15.f), 15.f);
        float e2 = __expf(2.f * z);
        float th = (e2 - 1.f) / (e2 + 1.f);          // tanh(z)
        float p  = __expf(th);
        P[(size_t)i * NF + ccn] = __float2half(p);
        rs += p;
      }
#pragma unroll
      for (int off = 1; off < 16; off <<= 1) rs += __shfl_xor(rs, off, 64);
      if (lr == 0) Dpart[(size_t)i * NDB + (cbase >> 6)] = rs;
    }
  }
}

// ---------------- invD[i] = 1 / sum_nb Dpart[i,nb] ----------------
__global__ __launch_bounds__(256) void k_invd(const float* __restrict__ Dpart,
                                              const int* __restrict__ meta,
                                              float* __restrict__ invD) {
  int i = blockIdx.x * 256 + threadIdx.x;
  if (i >= meta[1]) return;
  float d = 0.f;
#pragma unroll
  for (int q = 0; q < NDB; ++q) d += Dpart[(size_t)i * NDB + q];
  invD[i] = 1.0f / d;
}

// ---------------- out[b,f] = trig_a * (sum_i P*invD + (512-cnt)/3072) -----
__global__ __launch_bounds__(384) void k_final(const __half* __restrict__ P,
                                               const float* __restrict__ invD,
                                               const int* __restrict__ boff,
                                               const int* __restrict__ bcnt,
                                               const float* __restrict__ h,
                                               const float* __restrict__ x,
                                               const int* __restrict__ trig,
                                               float* __restrict__ out) {
  int b = blockIdx.x;
  int f0 = threadIdx.x * 8;                          // 384 threads x 8 = 3072
  int off = boff[b], cnt = bcnt[b];
  const __half* Pp = P + (size_t)off * NF + f0;
  const float*  iv = invD + off;
  float acc[8] = {};
  for (int t = 0; t < cnt; ++t) {
    int4 v = *(const int4*)(Pp + (size_t)t * NF);    // 8 halfs = 16B
    float ivt = iv[t];
    const __half2* h2 = (const __half2*)&v;
#pragma unroll
    for (int k = 0; k < 4; ++k) {
      float2 f2 = __half22float2(h2[k]);
      acc[2 * k]     += f2.x * ivt;
      acc[2 * k + 1] += f2.y * ivt;
    }
  }
  float uni = (float)(NS - cnt) * (1.0f / (float)NF);
  int tr = trig[b];
#pragma unroll
  for (int k = 0; k < 8; ++k) {
    int f = f0 + k;
    float ta = (f < KH) ? h[((size_t)b * NS + tr) * KH + f]
                        : x[((size_t)b * NS + tr) * SIN + f - KH];
    out[b * NF + f] = (acc[k] + uni) * ta;
  }
}

extern "C" void kernel_launch(void* const* d_in, const int* in_sizes, int n_in,
                              void* d_out, int out_size, void* d_ws, size_t ws_size,
                              hipStream_t stream) {
  const float* h_state = (const float*)d_in[0];
  const float* x       = (const float*)d_in[1];
  const int*   trigger = (const int*)d_in[2];
  const int*   mask    = (const int*)d_in[3];
  const float* Wa      = (const float*)d_in[4];
  const float* ba      = (const float*)d_in[5];
  const float* Ws      = (const float*)d_in[6];
  const float* bs      = (const float*)d_in[7];
  float*       out     = (float*)d_out;

  // workspace layout (bytes), total ~224 MB
  char* w = (char*)d_ws;
  u16*    Abf   = (u16*)w;                 w += (size_t)NM * NF * 2;
  u16*    WaT   = (u16*)w;                 w += (size_t)NF * NF * 2;
  __half* P     = (__half*)w;              w += (size_t)NM * NF * 2;
  float*  s     = (float*)w;               w += (size_t)NBAT * KH * 4;
  float*  base  = (float*)w;               w += (size_t)NBAT * NF * 4;
  float*  Dpart = (float*)w;               w += (size_t)NM * NDB * 4;
  float*  basep = (float*)Dpart;           // aliases Dpart (WAR: read before k_gemm)
  float*  invD  = (float*)w;               w += (size_t)NM * 4;
  int*    rowmap= (int*)w;                 w += (size_t)NM * 4;
  int*    bcnt  = (int*)w;                 w += 128;
  int*    boff  = (int*)w;                 w += 128;
  int*    meta  = (int*)w;                 w += 128;

  (void)in_sizes; (void)n_in; (void)out_size; (void)ws_size;

  k_cnt   <<<dim3(NBAT), 64, 0, stream>>>(mask, bcnt);
  k_scan  <<<dim3(1), 64, 0, stream>>>(bcnt, boff, meta);
  k_gather<<<dim3(NBAT), 512, 0, stream>>>(mask, boff, meta, rowmap);
  k_sum_h <<<dim3(NBAT, KH / 256), 256, 0, stream>>>(h_state, s);
  k_cvt_a <<<dim3(NM * (NF / 4) / 256), 256, 0, stream>>>(h_state, x, rowmap, meta, Abf);
  k_wat   <<<dim3(NF / 64, NF / 64), 256, 0, stream>>>(Wa, WaT);
  k_base1 <<<dim3(NF / 256, KC), 256, 0, stream>>>(s, Ws, basep);
  k_base2 <<<dim3(NBAT, NF / 256), 256, 0, stream>>>(basep, ba, bs, base);
  k_gemm  <<<dim3((NF / 256) * (NM / 256)), 512, 0, stream>>>(Abf, WaT, base, rowmap, meta, P, Dpart);
  k_invd  <<<dim3(NM / 256), 256, 0, stream>>>(Dpart, meta, invD);
  k_final <<<dim3(NBAT), 384, 0, stream>>>(P, invD, boff, bcnt, h_state, x, trigger, out);
}

// Round 6
// 423.033 us; speedup vs baseline: 2.1542x; 1.0987x over previous
//
#include <hip/hip_runtime.h>
#include <hip/hip_bf16.h>
#include <hip/hip_fp16.h>

// Decoder_22273700397282 on MI355X (gfx950)
// out[b,f] = trigger_a[b,f] * sum_t softmax_f(tanh(a@Wa + ba + s@Ws + bs))[t,f]
// mask==0 rows -> exactly 1/3072 per feature (handled analytically).
//
// R6: (1) vmcnt retune in the 8-phase GEMM: uniform vmcnt(6) per phase
// (6-phase stage->read lead; waits only on >=4-phase-old loads) instead of
// vmcnt(4)@ph4/ph8 which drained 2-phase-old loads (HBM-latency stall).
// (2) k_final split into a deterministic two-pass chunked reduction
// (R5's 32-block version starved 224 CUs).

namespace {
constexpr int SIN  = 1024;            // IN_SIZE
constexpr int KH   = 2048;            // 2*IN
constexpr int NF   = 3072;            // 3*IN = GEMM K and N
constexpr int NBAT = 32;
constexpr int NS   = 512;
constexpr int NM   = NBAT * NS;       // 16384 worst-case GEMM rows
constexpr int NDB  = NF / 64;         // 48 Dpart column blocks
constexpr int KC   = 8;               // k-chunks for k_base1
constexpr int NKT  = NF / 64;         // 48 K-tiles of 64
constexpr int NCH  = 8;               // 64-row chunks per batch (<=512 rows)
}

typedef unsigned short u16;
typedef __bf16 bf16x8 __attribute__((ext_vector_type(8)));
typedef float  f32x4  __attribute__((ext_vector_type(4)));

#define ASYNC_CP16(gptr, lptr)                                                              \
  __builtin_amdgcn_global_load_lds((__attribute__((address_space(1))) void*)(gptr),         \
                                   (__attribute__((address_space(3))) void*)(lptr), 16, 0, 0)

__device__ __forceinline__ u16 f2b(float f) {
  union { float f; unsigned u; } v; v.f = f;
  unsigned u = v.u;
  u += 0x7FFFu + ((u >> 16) & 1u);     // round-to-nearest-even
  return (u16)(u >> 16);
}

// ---------------- compaction: counts ----------------
__global__ __launch_bounds__(64) void k_cnt(const int* __restrict__ mask,
                                            int* __restrict__ bcnt) {
  int b = blockIdx.x, t = threadIdx.x;
  int c = 0;
#pragma unroll
  for (int i = 0; i < NS / 64; ++i) c += mask[b * NS + i * 64 + t];
#pragma unroll
  for (int off = 32; off >= 1; off >>= 1) c += __shfl_down(c, off, 64);
  if (t == 0) bcnt[b] = c;
}

// ---------------- compaction: scan ----------------
__global__ __launch_bounds__(64) void k_scan(const int* __restrict__ bcnt,
                                             int* __restrict__ boff,
                                             int* __restrict__ meta) {
  if (threadIdx.x == 0) {
    int run = 0;
    for (int b = 0; b < NBAT; ++b) { boff[b] = run; run += bcnt[b]; }
    meta[0] = run;                       // Mc
    meta[1] = (run + 255) & ~255;        // McPad (256-row tiles)
  }
}

// ---------------- compaction: gather ----------------
__global__ __launch_bounds__(512) void k_gather(const int* __restrict__ mask,
                                                const int* __restrict__ boff,
                                                const int* __restrict__ meta,
                                                int* __restrict__ rowmap) {
  __shared__ int ps[NS];
  int b = blockIdx.x, t = threadIdx.x;
  int m = mask[b * NS + t];
  ps[t] = m;
  __syncthreads();
#pragma unroll
  for (int off = 1; off < NS; off <<= 1) {
    int v = (t >= off) ? ps[t - off] : 0;
    __syncthreads();
    ps[t] += v;
    __syncthreads();
  }
  if (m) rowmap[boff[b] + ps[t] - m] = b * NS + t;
  if (b == 0) {                          // zero-pad rowmap up to McPad
    int Mc = meta[0], McPad = meta[1];
    if (Mc + t < McPad) rowmap[Mc + t] = 0;
  }
}

// ---------------- s[b,k] = sum_t h[b,t,k] ----------------
__global__ __launch_bounds__(256) void k_sum_h(const float* __restrict__ h,
                                               float* __restrict__ s) {
  int b = blockIdx.x;
  int d = blockIdx.y * 256 + threadIdx.x;
  const float* p = h + (size_t)b * NS * KH + d;
  float acc = 0.f;
#pragma unroll 8
  for (int t = 0; t < NS; ++t) acc += p[(size_t)t * KH];
  s[b * KH + d] = acc;
}

// ---------------- base partials: reads Ws once ----------------
__global__ __launch_bounds__(256) void k_base1(const float* __restrict__ s,
                                               const float* __restrict__ Ws,
                                               float* __restrict__ basep) {
  __shared__ float sT[NBAT][KH / KC];      // [32][256] = 32 KB
  int f  = blockIdx.x * 256 + threadIdx.x;
  int k0 = blockIdx.y * (KH / KC);
  for (int it = 0; it < NBAT; ++it) {
    int idx = it * 256 + threadIdx.x;
    int b = idx >> 8, kk = idx & 255;
    sT[b][kk] = s[b * KH + k0 + kk];
  }
  __syncthreads();
  float acc[NBAT] = {};
  for (int k = 0; k < KH / KC; ++k) {
    float w = Ws[(size_t)(k0 + k) * NF + f];
#pragma unroll
    for (int b = 0; b < NBAT; ++b) acc[b] += sT[b][k] * w;
  }
#pragma unroll
  for (int b = 0; b < NBAT; ++b)
    basep[((size_t)blockIdx.y * NBAT + b) * NF + f] = acc[b];
}

__global__ __launch_bounds__(256) void k_base2(const float* __restrict__ basep,
                                               const float* __restrict__ ba,
                                               const float* __restrict__ bs,
                                               float* __restrict__ base) {
  int b = blockIdx.x;
  int f = blockIdx.y * 256 + threadIdx.x;
  float acc = 0.f;
#pragma unroll
  for (int kc = 0; kc < KC; ++kc) acc += basep[((size_t)kc * NBAT + b) * NF + f];
  base[b * NF + f] = acc + ba[f] + bs[f];
}

// ---------------- Abf[i,k] = bf16(concat(h,x)[rowmap[i],k]) ----------------
__global__ __launch_bounds__(256) void k_cvt_a(const float* __restrict__ h,
                                               const float* __restrict__ x,
                                               const int* __restrict__ rowmap,
                                               const int* __restrict__ meta,
                                               u16* __restrict__ A) {
  int tid = blockIdx.x * 256 + threadIdx.x;
  int i = tid / (NF / 4);
  if (i >= meta[1]) return;
  int k = (tid - i * (NF / 4)) * 4;
  ushort4 o;
  if (i >= meta[0]) {
    o.x = o.y = o.z = o.w = 0;
  } else {
    int ro = rowmap[i];
    int b = ro >> 9, t = ro & 511;
    const float* src = (k < KH) ? h + ((size_t)b * NS + t) * KH + k
                                : x + ((size_t)b * NS + t) * SIN + (k - KH);
    float4 v = *(const float4*)src;
    o.x = f2b(v.x); o.y = f2b(v.y); o.z = f2b(v.z); o.w = f2b(v.w);
  }
  *(ushort4*)(A + (size_t)i * NF + k) = o;
}

// ---------------- WaT[f,k] = bf16(Wa[k,f]) ----------------
__global__ __launch_bounds__(256) void k_wat(const float* __restrict__ Wa,
                                             u16* __restrict__ WaT) {
  __shared__ float tile[64][65];
  int k0 = blockIdx.x * 64, f0 = blockIdx.y * 64;
  int tid = threadIdx.x;
  int col4 = (tid & 15) * 4, row = tid >> 4;
#pragma unroll
  for (int rr = 0; rr < 64; rr += 16) {
    float4 v = *(const float4*)(Wa + (size_t)(k0 + row + rr) * NF + f0 + col4);
    tile[row + rr][col4 + 0] = v.x; tile[row + rr][col4 + 1] = v.y;
    tile[row + rr][col4 + 2] = v.z; tile[row + rr][col4 + 3] = v.w;
  }
  __syncthreads();
#pragma unroll
  for (int rr = 0; rr < 64; rr += 16) {
    int f = f0 + row + rr;
    ushort4 o;
    o.x = f2b(tile[col4 + 0][row + rr]); o.y = f2b(tile[col4 + 1][row + rr]);
    o.z = f2b(tile[col4 + 2][row + rr]); o.w = f2b(tile[col4 + 3][row + rr]);
    *(ushort4*)(WaT + (size_t)f * NF + k0 + col4) = o;
  }
}

// ---------------- main GEMM: 256x256 tile, 8-phase schedule ----------------
// lds[buf][mat][khalf]: [256][32] u16 subtile, chunk-XOR swizzled.
#define LDSOFF(row, gg) ((row) * 32 + ((((gg) ^ (((row) >> 1) & 3))) << 3))

#define LDB4(BUF, KS)                                                        \
  _Pragma("unroll") for (int nf = 0; nf < 4; ++nf) {                         \
    int rb = wc * 64 + nf * 16 + lr;                                         \
    bfr[nf] = *(const bf16x8*)&lds[BUF][1][KS][LDSOFF(rb, g)];               \
  }

#define LDA4(BUF, KS, MH)                                                    \
  _Pragma("unroll") for (int mf = 0; mf < 4; ++mf) {                         \
    int ra = wr * 128 + ((MH) * 4 + mf) * 16 + lr;                           \
    afr[mf] = *(const bf16x8*)&lds[BUF][0][KS][LDSOFF(ra, g)];               \
  }

#define MFMA16(MH)                                                           \
  _Pragma("unroll") for (int mf = 0; mf < 4; ++mf)                           \
  _Pragma("unroll") for (int nf = 0; nf < 4; ++nf)                           \
    acc[(MH) * 4 + mf][nf] = __builtin_amdgcn_mfma_f32_16x16x32_bf16(        \
        afr[mf], bfr[nf], acc[(MH) * 4 + mf][nf], 0, 0, 0);

// stage one K-half subtile (256x32 = 16 KB = 2 issues of 8 KB)
#define STAGE(SMAT, SBUF, SKS, SKT)                                          \
  if ((SKT) < NKT) {                                                         \
    _Pragma("unroll") for (int q = 0; q < 2; ++q) {                          \
      const u16* src = ((SMAT) ? pB[q] : pA[q]) + (SKT) * 64 + (SKS) * 32;   \
      ASYNC_CP16(src, &lds[SBUF][SMAT][SKS][q * 4096 + wid * 512]);          \
    }                                                                        \
  }

// Slot lead is 6 phases for every stage -> uniform vmcnt(6) per phase:
// at end of phase p we wait only on loads issued >=4 phases ago (landed).
#define PH(BUF, KS, MH, SMAT, SBUF, SKS, SKT)                                \
  {                                                                          \
    if ((MH) == 0) { LDB4(BUF, KS) }                                         \
    LDA4(BUF, KS, MH)                                                        \
    STAGE(SMAT, SBUF, SKS, SKT)                                              \
    __builtin_amdgcn_s_barrier();                                            \
    asm volatile("s_waitcnt lgkmcnt(0)" ::: "memory");                       \
    __builtin_amdgcn_s_setprio(1);                                           \
    MFMA16(MH)                                                               \
    __builtin_amdgcn_s_setprio(0);                                           \
    asm volatile("s_waitcnt vmcnt(6)" ::: "memory");                         \
    __builtin_amdgcn_s_barrier();                                            \
  }

__global__ __launch_bounds__(512, 2) void k_gemm(const u16* __restrict__ A,
                                                 const u16* __restrict__ Wt,
                                                 const float* __restrict__ base,
                                                 const int* __restrict__ rowmap,
                                                 const int* __restrict__ meta,
                                                 __half* __restrict__ P,
                                                 float* __restrict__ Dpart) {
  __shared__ __align__(16) u16 lds[2][2][2][8192];   // 128 KB
  const int MT   = meta[1] >> 8;                      // active M-tiles
  const int nact = MT * 12;
  const int flat = blockIdx.x;
  if (flat >= nact) return;
  // bijective XCD-chunked swizzle over the active blocks
  const int qx = nact >> 3, rx = nact & 7;
  const int xcd = flat & 7, idx = flat >> 3;
  const int swz = (xcd < rx) ? xcd * (qx + 1) + idx
                             : rx * (qx + 1) + (xcd - rx) * qx + idx;
  const int mt = swz / 12, nt = swz - mt * 12;        // n fastest: A-panel L2 reuse
  const int r0 = mt << 8, c0 = nt << 8;

  const int tid = threadIdx.x;
  const int wid = tid >> 6, lane = tid & 63;
  const int wr = wid >> 2, wc = wid & 3;              // 2M x 4N waves, 128x64 each
  const int g = lane >> 4, lr = lane & 15;

  // per-lane staging source pointers (swizzle folded into source column)
  const u16* pA[2]; const u16* pB[2];
#pragma unroll
  for (int q = 0; q < 2; ++q) {
    int c = q * 512 + tid;
    int row = c >> 2;
    int kc8 = (((c & 3) ^ ((row >> 1) & 3)) << 3);
    pA[q] = A  + (size_t)(r0 + row) * NF + kc8;
    pB[q] = Wt + (size_t)(c0 + row) * NF + kc8;
  }

  f32x4 acc[8][4] = {};
  bf16x8 afr[4], bfr[4];

  // prologue: kt0 complete + kt1 K-half0 (12 loads); drain s1,s2 (leave 8)
  STAGE(0, 0, 0, 0) STAGE(1, 0, 0, 0)
  STAGE(0, 0, 1, 0) STAGE(1, 0, 1, 0)
  STAGE(0, 1, 0, 1) STAGE(1, 1, 0, 1)
  asm volatile("s_waitcnt vmcnt(8)" ::: "memory");
  __builtin_amdgcn_s_barrier();

  // main loop: iteration computes kt=2i (buf0) and kt=2i+1 (buf1).
  // Stage slots (6-phase stage->read lead each):
  //  ph1: A-ks1(kt2i+1)->b1  ph2: B-ks1(kt2i+1)->b1
  //  ph3: A-ks0(kt2i+2)->b0  ph4: B-ks0(kt2i+2)->b0
  //  ph5: A-ks1(kt2i+2)->b0  ph6: B-ks1(kt2i+2)->b0
  //  ph7: A-ks0(kt2i+3)->b1  ph8: B-ks0(kt2i+3)->b1
#pragma unroll 1
  for (int i = 0; i < NKT / 2; ++i) {
    const int kt1 = 2 * i + 1, kt2 = 2 * i + 2, kt3 = 2 * i + 3;
    PH(0, 0, 0, 0, 1, 1, kt1)
    PH(0, 0, 1, 1, 1, 1, kt1)
    PH(0, 1, 0, 0, 0, 0, kt2)
    PH(0, 1, 1, 1, 0, 0, kt2)
    PH(1, 0, 0, 0, 0, 1, kt2)
    PH(1, 0, 1, 1, 0, 1, kt2)
    PH(1, 1, 0, 0, 1, 0, kt3)
    PH(1, 1, 1, 1, 1, 0, kt3)
  }

  // epilogue: z = acc + base; P = exp(tanh(z)); Dpart rowsums
  const int cbase = c0 + wc * 64;
#pragma unroll
  for (int mf = 0; mf < 8; ++mf) {
#pragma unroll
    for (int j = 0; j < 4; ++j) {
      int i = r0 + wr * 128 + mf * 16 + g * 4 + j;   // compacted row
      int b = rowmap[i] >> 9;                        // original batch
      float rs = 0.f;
#pragma unroll
      for (int nf = 0; nf < 4; ++nf) {
        int ccn = cbase + nf * 16 + lr;
        float z  = acc[mf][nf][j] + base[b * NF + ccn];
        z        = fminf(fmaxf(z, -15.f), 15.f);
        float e2 = __expf(2.f * z);
        float th = (e2 - 1.f) / (e2 + 1.f);          // tanh(z)
        float p  = __expf(th);
        P[(size_t)i * NF + ccn] = __float2half(p);
        rs += p;
      }
#pragma unroll
      for (int off = 1; off < 16; off <<= 1) rs += __shfl_xor(rs, off, 64);
      if (lr == 0) Dpart[(size_t)i * NDB + (cbase >> 6)] = rs;
    }
  }
}

// ---------------- invD[i] = 1 / sum_nb Dpart[i,nb] ----------------
__global__ __launch_bounds__(256) void k_invd(const float* __restrict__ Dpart,
                                              const int* __restrict__ meta,
                                              float* __restrict__ invD) {
  int i = blockIdx.x * 256 + threadIdx.x;
  if (i >= meta[1]) return;
  float d = 0.f;
#pragma unroll
  for (int q = 0; q < NDB; ++q) d += Dpart[(size_t)i * NDB + q];
  invD[i] = 1.0f / d;
}

// ---------------- final pass 1: per-(batch,chunk) partial sums ----------
// pb[(b*NCH+j)*NF + f] = sum over rows [boff+64j, min(boff+cnt, boff+64j+64))
__global__ __launch_bounds__(256) void k_final1(const __half* __restrict__ P,
                                                const float* __restrict__ invD,
                                                const int* __restrict__ boff,
                                                const int* __restrict__ bcnt,
                                                float* __restrict__ pb) {
  int c = blockIdx.x;                                // b*NCH + j
  int b = c >> 3, j = c & 7;
  int f = blockIdx.y * 256 + threadIdx.x;
  int cnt = bcnt[b];
  int lo = j * 64, hi = min(cnt, lo + 64);
  int off = boff[b];
  float acc = 0.f;
  for (int t = lo; t < hi; ++t)
    acc += __half2float(P[(size_t)(off + t) * NF + f]) * invD[off + t];
  pb[(size_t)c * NF + f] = acc;
}

// ---------------- final pass 2: combine + uniform + trigger mult ---------
__global__ __launch_bounds__(256) void k_final2(const float* __restrict__ pb,
                                                const int* __restrict__ bcnt,
                                                const float* __restrict__ h,
                                                const float* __restrict__ x,
                                                const int* __restrict__ trig,
                                                float* __restrict__ out) {
  int b = blockIdx.x;
  int f = blockIdx.y * 256 + threadIdx.x;
  float acc = 0.f;
#pragma unroll
  for (int j = 0; j < NCH; ++j) acc += pb[(size_t)(b * NCH + j) * NF + f];
  acc += (float)(NS - bcnt[b]) * (1.0f / (float)NF);
  int tr = trig[b];
  float ta = (f < KH) ? h[((size_t)b * NS + tr) * KH + f]
                      : x[((size_t)b * NS + tr) * SIN + f - KH];
  out[b * NF + f] = acc * ta;
}

extern "C" void kernel_launch(void* const* d_in, const int* in_sizes, int n_in,
                              void* d_out, int out_size, void* d_ws, size_t ws_size,
                              hipStream_t stream) {
  const float* h_state = (const float*)d_in[0];
  const float* x       = (const float*)d_in[1];
  const int*   trigger = (const int*)d_in[2];
  const int*   mask    = (const int*)d_in[3];
  const float* Wa      = (const float*)d_in[4];
  const float* ba      = (const float*)d_in[5];
  const float* Ws      = (const float*)d_in[6];
  const float* bs      = (const float*)d_in[7];
  float*       out     = (float*)d_out;

  // workspace layout (bytes), total ~224 MB
  char* w = (char*)d_ws;
  u16*    Abf   = (u16*)w;                 w += (size_t)NM * NF * 2;
  u16*    WaT   = (u16*)w;                 w += (size_t)NF * NF * 2;
  __half* P     = (__half*)w;              w += (size_t)NM * NF * 2;
  float*  s     = (float*)w;               w += (size_t)NBAT * KH * 4;
  float*  base  = (float*)w;               w += (size_t)NBAT * NF * 4;
  float*  Dpart = (float*)w;               w += (size_t)NM * NDB * 4;
  float*  basep = (float*)Dpart;           // aliases Dpart (read before k_gemm)
  float*  pb    = (float*)Dpart;           // aliases Dpart (written after k_invd)
  float*  invD  = (float*)w;               w += (size_t)NM * 4;
  int*    rowmap= (int*)w;                 w += (size_t)NM * 4;
  int*    bcnt  = (int*)w;                 w += 128;
  int*    boff  = (int*)w;                 w += 128;
  int*    meta  = (int*)w;                 w += 128;

  (void)in_sizes; (void)n_in; (void)out_size; (void)ws_size;

  k_cnt   <<<dim3(NBAT), 64, 0, stream>>>(mask, bcnt);
  k_scan  <<<dim3(1), 64, 0, stream>>>(bcnt, boff, meta);
  k_gather<<<dim3(NBAT), 512, 0, stream>>>(mask, boff, meta, rowmap);
  k_sum_h <<<dim3(NBAT, KH / 256), 256, 0, stream>>>(h_state, s);
  k_cvt_a <<<dim3(NM * (NF / 4) / 256), 256, 0, stream>>>(h_state, x, rowmap, meta, Abf);
  k_wat   <<<dim3(NF / 64, NF / 64), 256, 0, stream>>>(Wa, WaT);
  k_base1 <<<dim3(NF / 256, KC), 256, 0, stream>>>(s, Ws, basep);
  k_base2 <<<dim3(NBAT, NF / 256), 256, 0, stream>>>(basep, ba, bs, base);
  k_gemm  <<<dim3((NF / 256) * (NM / 256)), 512, 0, stream>>>(Abf, WaT, base, rowmap, meta, P, Dpart);
  k_invd  <<<dim3(NM / 256), 256, 0, stream>>>(Dpart, meta, invD);
  k_final1<<<dim3(NBAT * NCH, NF / 256), 256, 0, stream>>>(P, invD, boff, bcnt, pb);
  k_final2<<<dim3(NBAT, NF / 256), 256, 0, stream>>>(pb, bcnt, h_state, x, trigger, out);
}